// Round 11
// baseline (132.404 us; speedup 1.0000x reference)
//
#include <hip/hip_runtime.h>

#define DFEAT 16
#define NPB 64              // nodes per bucket
#define NPB_SHIFT 6
#define EB 16384            // edges per bin block
#define BIN_THREADS 512
#define BATCH (EB / BIN_THREADS)   // 32
#define SORT_CAP 3072       // bucket size: mean 2048, sigma ~45 -> 22 sigma headroom

typedef float f32x4 __attribute__((ext_vector_type(4)));

// Pass 1: per-block bucket histogram. Batched loads, non-returning LDS atomics.
__global__ void na_bin_kernel(const int* __restrict__ edge_dst,
                              int* __restrict__ hist,
                              int E, int B, int nblocks) {
    extern __shared__ int h[];   // B counters
    const int b = blockIdx.x;
    const int t = threadIdx.x;
    for (int i = t; i < B; i += BIN_THREADS) h[i] = 0;
    __syncthreads();
    const int base = b * EB;

    #pragma unroll
    for (int c = 0; c < BATCH; c += 8) {
        int d[8];
        #pragma unroll
        for (int jj = 0; jj < 8; ++jj) {
            int e = base + (c + jj) * BIN_THREADS + t;
            d[jj] = (e < E) ? edge_dst[e] : -1;
        }
        #pragma unroll
        for (int jj = 0; jj < 8; ++jj)
            if (d[jj] >= 0) atomicAdd(&h[d[jj] >> NPB_SHIFT], 1);  // ds_add
    }
    __syncthreads();
    for (int i = t; i < B; i += BIN_THREADS)
        hist[(size_t)i * nblocks + b] = h[i];      // bucket-major matrix
}

// S1: one wave per bucket — exclusive scan of the bucket's row (in place),
// bucket total out. Pure shfl, no barriers.
__global__ void na_row_scan(int* __restrict__ hist,
                            int* __restrict__ bucketTotal,
                            int nblocks) {
    const int k = blockIdx.x;
    const int t = threadIdx.x;   // 64
    int* row = hist + (size_t)k * nblocks;
    const int CPT = (nblocks + 63) >> 6;
    const int beg = min(t * CPT, nblocks);
    const int end = min(beg + CPT, nblocks);

    int s = 0;
    for (int i = beg; i < end; ++i) s += row[i];
    int inc = s;
    #pragma unroll
    for (int d = 1; d < 64; d <<= 1) {
        int u = __shfl_up(inc, d);
        if (t >= d) inc += u;
    }
    int run = inc - s;           // exclusive prefix for this thread's chunk
    for (int i = beg; i < end; ++i) {
        int c = row[i];
        row[i] = run;
        run += c;
    }
    if (t == 63) bucketTotal[k] = inc;
}

// S2: single WAVE — exclusive scan of bucket totals -> bucketBase[0..B].
__global__ void na_base_scan(const int* __restrict__ bucketTotal,
                             int* __restrict__ bucketBase,
                             int B) {
    const int t = threadIdx.x;   // 64
    const int CPT = (B + 63) >> 6;
    const int beg = min(t * CPT, B);
    const int end = min(beg + CPT, B);
    int s = 0;
    for (int i = beg; i < end; ++i) s += bucketTotal[i];
    int inc = s;
    #pragma unroll
    for (int d = 1; d < 64; d <<= 1) {
        int u = __shfl_up(inc, d);
        if (t >= d) inc += u;
    }
    int run = inc - s;
    for (int i = beg; i < end; ++i) {
        int c = bucketTotal[i];
        bucketBase[i] = run;
        run += c;
    }
    if (t == 63) bucketBase[B] = inc;
}

// Pass 3: batched re-read of edge_dst, LDS cursors = bucketBase + row prefix,
// packed edge written straight to its final cell. No global atomics.
__global__ void na_scatter_fused(const int* __restrict__ edge_dst,
                                 const int* __restrict__ hist,
                                 const int* __restrict__ bucketBase,
                                 int* __restrict__ binned,
                                 int E, int B, int nblocks) {
    extern __shared__ int h[];   // B cursors
    const int b = blockIdx.x;
    const int t = threadIdx.x;
    for (int i = t; i < B; i += BIN_THREADS)
        h[i] = bucketBase[i] + hist[(size_t)i * nblocks + b];
    __syncthreads();
    const int base = b * EB;

    #pragma unroll
    for (int c = 0; c < BATCH; c += 8) {
        int d[8];
        #pragma unroll
        for (int jj = 0; jj < 8; ++jj) {
            int e = base + (c + jj) * BIN_THREADS + t;
            d[jj] = (e < E) ? edge_dst[e] : -1;
        }
        #pragma unroll
        for (int jj = 0; jj < 8; ++jj) {
            if (d[jj] >= 0) {
                int n = d[jj];
                int e = base + (c + jj) * BIN_THREADS + t;
                int pos = atomicAdd(&h[n >> NPB_SHIFT], 1);
                binned[pos] = ((n & (NPB - 1)) << 22) | e;   // e < 2^22
            }
        }
    }
}

// Pass 4 (fused sort + gather): one block per bucket, 7 blocks/CU resident.
// Counting-sort in LDS (binned read twice, 2nd is L2-hot); sorted[] holds
// pre-shifted byte offsets. Gather: 16 lanes/node (4 edge-slots x 4 quads),
// non-temporal x loads (zero reuse), nt out stores.
__global__ __launch_bounds__(256, 7)
void na_sort_gather(const float* __restrict__ x,
                    const int* __restrict__ binned,
                    const int* __restrict__ bucketBase,
                    float* __restrict__ out,
                    int N) {
    __shared__ int sorted[SORT_CAP];
    __shared__ int cnt[NPB];
    __shared__ int cur[NPB];
    __shared__ int excl[NPB + 1];

    const int k = blockIdx.x;
    const int t = threadIdx.x;   // 256

    const int beg = bucketBase[k];
    const int end = bucketBase[k + 1];
    const int sz = end - beg;

    if (t < NPB) { cnt[t] = 0; cur[t] = 0; }
    __syncthreads();

    if (sz <= SORT_CAP) {
        // Phase a: 64-bin histogram (non-returning LDS atomics).
        for (int j = t; j < sz; j += 256)
            atomicAdd(&cnt[binned[beg + j] >> 22], 1);
        __syncthreads();
        // Wave-parallel exclusive scan over 64 counts (wave 0 only).
        if (t < 64) {
            int v = cnt[t];
            int inc = v;
            #pragma unroll
            for (int d = 1; d < 64; d <<= 1) {
                int u = __shfl_up(inc, d);
                if (t >= d) inc += u;
            }
            excl[t] = inc - v;
            if (t == 63) excl[NPB] = inc;
        }
        __syncthreads();
        // Phase c: re-read (L2-hot) + counting-sort scatter within LDS.
        // Store byte offset (e * 64) directly.
        for (int j = t; j < sz; j += 256) {
            int v = binned[beg + j];
            int d = v >> 22;
            int r = atomicAdd(&cur[d], 1);
            sorted[excl[d] + r] = (v & 0x3FFFFF) << 6;
        }
        __syncthreads();

        // Phase d: float4 gather, 16 lanes/node (4 edge-slots x 4 quads).
        const int g = t >> 4;          // node group 0..15
        const int lane16 = t & 15;
        const int es = lane16 >> 2;    // edge slot 0..3
        const int q = lane16 & 3;      // feature quad 0..3
        const char* xb = reinterpret_cast<const char*>(x) + q * 16;

        for (int ln = g; ln < NPB; ln += 16) {
            int n = k * NPB + ln;
            if (n >= N) break;         // uniform within the 16-lane group
            int lbeg = excl[ln], lend = excl[ln + 1];
            f32x4 acc = {0.f, 0.f, 0.f, 0.f};

            int i = lbeg + es;
            for (; i + 12 < lend; i += 16) {   // 4 independent loads in flight
                int o0 = sorted[i];
                int o1 = sorted[i + 4];
                int o2 = sorted[i + 8];
                int o3 = sorted[i + 12];
                f32x4 v0 = __builtin_nontemporal_load((const f32x4*)(xb + o0));
                f32x4 v1 = __builtin_nontemporal_load((const f32x4*)(xb + o1));
                f32x4 v2 = __builtin_nontemporal_load((const f32x4*)(xb + o2));
                f32x4 v3 = __builtin_nontemporal_load((const f32x4*)(xb + o3));
                acc += (v0 + v1) + (v2 + v3);
            }
            for (; i < lend; i += 4) {
                f32x4 v0 = __builtin_nontemporal_load((const f32x4*)(xb + sorted[i]));
                acc += v0;
            }

            // Butterfly-reduce across the 4 edge slots (masks 4, 8).
            #pragma unroll
            for (int c = 0; c < 4; ++c) {
                acc[c] += __shfl_xor(acc[c], 4);
                acc[c] += __shfl_xor(acc[c], 8);
            }

            float s = rsqrtf((float)(lend - lbeg) + 1.0f);
            if (es == 0) {
                f32x4 r = acc * s;
                __builtin_nontemporal_store(
                    r, (f32x4*)(reinterpret_cast<char*>(out) + (size_t)n * 64 + q * 16));
            }
        }
    } else {
        // Never expected (sz > 22 sigma above mean); slow but correct.
        const int ln = t >> 2;
        const int q = t & 3;
        const float4* x4 = reinterpret_cast<const float4*>(x);
        int n = k * NPB + ln;
        if (n < N) {
            float ax = 0.f, ay = 0.f, az = 0.f, aw = 0.f;
            int deg = 0;
            for (int j = 0; j < sz; ++j) {
                int v = binned[beg + j];
                if ((v >> 22) == ln) {
                    float4 vv = x4[(size_t)(v & 0x3FFFFF) * 4 + q];
                    ax += vv.x; ay += vv.y; az += vv.z; aw += vv.w;
                    ++deg;
                }
            }
            float s = rsqrtf((float)deg + 1.0f);
            float4 r; r.x = ax * s; r.y = ay * s; r.z = az * s; r.w = aw * s;
            reinterpret_cast<float4*>(out)[(size_t)n * 4 + q] = r;
        }
    }
}

extern "C" void kernel_launch(void* const* d_in, const int* in_sizes, int n_in,
                              void* d_out, int out_size, void* d_ws, size_t ws_size,
                              hipStream_t stream) {
    const float* x        = (const float*)d_in[0];
    const int*   edge_dst = (const int*)d_in[1];
    float*       out      = (float*)d_out;

    const int E = in_sizes[1];                    // 3,200,000
    const int N = out_size / DFEAT;               // 100,000
    const int B = (N + NPB - 1) >> NPB_SHIFT;     // 1563 buckets
    const int nblocks = (E + EB - 1) / EB;        // 196 bin blocks
    const int M = B * nblocks;                    // ~306k hist entries

    // ws: binned(int E) | hist(int M) | bucketTotal(B) | bucketBase(B+1) ~ 14 MB
    int* binned      = (int*)d_ws;
    int* hist        = binned + E;
    int* bucketTotal = hist + M;
    int* bucketBase  = bucketTotal + B;

    na_bin_kernel<<<nblocks, BIN_THREADS, B * sizeof(int), stream>>>(
        edge_dst, hist, E, B, nblocks);
    na_row_scan<<<B, 64, 0, stream>>>(hist, bucketTotal, nblocks);
    na_base_scan<<<1, 64, 0, stream>>>(bucketTotal, bucketBase, B);
    na_scatter_fused<<<nblocks, BIN_THREADS, B * sizeof(int), stream>>>(
        edge_dst, hist, bucketBase, binned, E, B, nblocks);
    na_sort_gather<<<B, 256, 0, stream>>>(x, binned, bucketBase, out, N);
}

// Round 12
// 120.359 us; speedup vs baseline: 1.1001x; 1.1001x over previous
//
#include <hip/hip_runtime.h>

#define DFEAT 16
#define NPB 64              // nodes per bucket
#define NPB_SHIFT 6
#define EB 16384            // edges per bin block
#define BIN_THREADS 512
#define BATCH (EB / BIN_THREADS)   // 32
#define SORT_CAP 3072       // bucket size: mean 2048, sigma ~45 -> 22 sigma headroom

// Pass 1: per-block bucket histogram. Batched loads, non-returning LDS atomics.
__global__ void na_bin_kernel(const int* __restrict__ edge_dst,
                              int* __restrict__ hist,
                              int E, int B, int nblocks) {
    extern __shared__ int h[];   // B counters
    const int b = blockIdx.x;
    const int t = threadIdx.x;
    for (int i = t; i < B; i += BIN_THREADS) h[i] = 0;
    __syncthreads();
    const int base = b * EB;

    #pragma unroll
    for (int c = 0; c < BATCH; c += 8) {
        int d[8];
        #pragma unroll
        for (int jj = 0; jj < 8; ++jj) {
            int e = base + (c + jj) * BIN_THREADS + t;
            d[jj] = (e < E) ? edge_dst[e] : -1;
        }
        #pragma unroll
        for (int jj = 0; jj < 8; ++jj)
            if (d[jj] >= 0) atomicAdd(&h[d[jj] >> NPB_SHIFT], 1);  // ds_add
    }
    __syncthreads();
    for (int i = t; i < B; i += BIN_THREADS)
        hist[(size_t)i * nblocks + b] = h[i];      // bucket-major matrix
}

// S1: one wave per bucket — exclusive scan of the bucket's row (in place),
// bucket total out. Pure shfl, no barriers.
__global__ void na_row_scan(int* __restrict__ hist,
                            int* __restrict__ bucketTotal,
                            int nblocks) {
    const int k = blockIdx.x;
    const int t = threadIdx.x;   // 64
    int* row = hist + (size_t)k * nblocks;
    const int CPT = (nblocks + 63) >> 6;
    const int beg = min(t * CPT, nblocks);
    const int end = min(beg + CPT, nblocks);

    int s = 0;
    for (int i = beg; i < end; ++i) s += row[i];
    int inc = s;
    #pragma unroll
    for (int d = 1; d < 64; d <<= 1) {
        int u = __shfl_up(inc, d);
        if (t >= d) inc += u;
    }
    int run = inc - s;           // exclusive prefix for this thread's chunk
    for (int i = beg; i < end; ++i) {
        int c = row[i];
        row[i] = run;
        run += c;
    }
    if (t == 63) bucketTotal[k] = inc;
}

// S2: single block — exclusive scan of bucket totals -> bucketBase[0..B].
__global__ void na_base_scan(const int* __restrict__ bucketTotal,
                             int* __restrict__ bucketBase,
                             int B) {
    __shared__ int lds[1024];
    const int t = threadIdx.x;
    const int CPT = (B + 1023) >> 10;
    const int beg = min(t * CPT, B);
    const int end = min(beg + CPT, B);
    int s = 0;
    for (int i = beg; i < end; ++i) s += bucketTotal[i];
    lds[t] = s;
    __syncthreads();
    for (int off = 1; off < 1024; off <<= 1) {
        int add = (t >= off) ? lds[t - off] : 0;
        __syncthreads();
        lds[t] += add;
        __syncthreads();
    }
    int run = lds[t] - s;
    for (int i = beg; i < end; ++i) {
        int c = bucketTotal[i];
        bucketBase[i] = run;
        run += c;
    }
    if (t == 1023) bucketBase[B] = lds[1023];
}

// Pass 3: batched re-read of edge_dst, LDS cursors = bucketBase + row prefix,
// packed edge written straight to its final cell. No global atomics.
__global__ void na_scatter_fused(const int* __restrict__ edge_dst,
                                 const int* __restrict__ hist,
                                 const int* __restrict__ bucketBase,
                                 int* __restrict__ binned,
                                 int E, int B, int nblocks) {
    extern __shared__ int h[];   // B cursors
    const int b = blockIdx.x;
    const int t = threadIdx.x;
    for (int i = t; i < B; i += BIN_THREADS)
        h[i] = bucketBase[i] + hist[(size_t)i * nblocks + b];
    __syncthreads();
    const int base = b * EB;

    #pragma unroll
    for (int c = 0; c < BATCH; c += 8) {
        int d[8];
        #pragma unroll
        for (int jj = 0; jj < 8; ++jj) {
            int e = base + (c + jj) * BIN_THREADS + t;
            d[jj] = (e < E) ? edge_dst[e] : -1;
        }
        #pragma unroll
        for (int jj = 0; jj < 8; ++jj) {
            if (d[jj] >= 0) {
                int n = d[jj];
                int e = base + (c + jj) * BIN_THREADS + t;
                int pos = atomicAdd(&h[n >> NPB_SHIFT], 1);
                binned[pos] = ((n & (NPB - 1)) << 22) | e;   // e < 2^22
            }
        }
    }
}

// Pass 4 (fused sort + gather): one block per bucket, 7 blocks/CU resident.
// Counting-sort in LDS (binned read twice, 2nd is L2-hot), then float4 gather
// with 16 lanes per node = 4 edge-slots x 4 feature-quads.
__global__ __launch_bounds__(256, 7)
void na_sort_gather(const float* __restrict__ x,
                    const int* __restrict__ binned,
                    const int* __restrict__ bucketBase,
                    float* __restrict__ out,
                    int N) {
    __shared__ int sorted[SORT_CAP];
    __shared__ int cnt[NPB];
    __shared__ int cur[NPB];
    __shared__ int excl[NPB + 1];

    const int k = blockIdx.x;
    const int t = threadIdx.x;   // 256

    const int beg = bucketBase[k];
    const int end = bucketBase[k + 1];
    const int sz = end - beg;

    if (t < NPB) { cnt[t] = 0; cur[t] = 0; }
    __syncthreads();

    if (sz <= SORT_CAP) {
        // Phase a: 64-bin histogram (non-returning LDS atomics).
        for (int j = t; j < sz; j += 256)
            atomicAdd(&cnt[binned[beg + j] >> 22], 1);
        __syncthreads();
        // Wave-parallel exclusive scan over 64 counts (wave 0 only).
        if (t < 64) {
            int v = cnt[t];
            int inc = v;
            #pragma unroll
            for (int d = 1; d < 64; d <<= 1) {
                int u = __shfl_up(inc, d);
                if (t >= d) inc += u;
            }
            excl[t] = inc - v;
            if (t == 63) excl[NPB] = inc;
        }
        __syncthreads();
        // Phase c: re-read (L2-hot) + counting-sort scatter within LDS.
        for (int j = t; j < sz; j += 256) {
            int v = binned[beg + j];
            int d = v >> 22;
            int r = atomicAdd(&cur[d], 1);
            sorted[excl[d] + r] = v & 0x3FFFFF;
        }
        __syncthreads();

        // Phase d: float4 gather, 16 lanes/node (4 edge-slots x 4 quads).
        const int g = t >> 4;          // node group 0..15
        const int lane16 = t & 15;
        const int es = lane16 >> 2;    // edge slot 0..3
        const int q = lane16 & 3;      // feature quad 0..3
        const float4* x4 = reinterpret_cast<const float4*>(x);

        for (int ln = g; ln < NPB; ln += 16) {
            int n = k * NPB + ln;
            if (n >= N) break;         // uniform within the 16-lane group
            int lbeg = excl[ln], lend = excl[ln + 1];
            float ax = 0.f, ay = 0.f, az = 0.f, aw = 0.f;

            int i = lbeg + es;
            for (; i + 12 < lend; i += 16) {   // 4 independent loads in flight
                int e0 = sorted[i];
                int e1 = sorted[i + 4];
                int e2 = sorted[i + 8];
                int e3 = sorted[i + 12];
                float4 v0 = x4[(size_t)e0 * 4 + q];
                float4 v1 = x4[(size_t)e1 * 4 + q];
                float4 v2 = x4[(size_t)e2 * 4 + q];
                float4 v3 = x4[(size_t)e3 * 4 + q];
                ax += (v0.x + v1.x) + (v2.x + v3.x);
                ay += (v0.y + v1.y) + (v2.y + v3.y);
                az += (v0.z + v1.z) + (v2.z + v3.z);
                aw += (v0.w + v1.w) + (v2.w + v3.w);
            }
            for (; i < lend; i += 4) {
                int e0 = sorted[i];
                float4 v0 = x4[(size_t)e0 * 4 + q];
                ax += v0.x; ay += v0.y; az += v0.z; aw += v0.w;
            }

            // Butterfly-reduce across the 4 edge slots (masks 4, 8).
            ax += __shfl_xor(ax, 4); ay += __shfl_xor(ay, 4);
            az += __shfl_xor(az, 4); aw += __shfl_xor(aw, 4);
            ax += __shfl_xor(ax, 8); ay += __shfl_xor(ay, 8);
            az += __shfl_xor(az, 8); aw += __shfl_xor(aw, 8);

            float s = rsqrtf((float)(lend - lbeg) + 1.0f);
            if (es == 0) {
                float4 r; r.x = ax * s; r.y = ay * s; r.z = az * s; r.w = aw * s;
                reinterpret_cast<float4*>(out)[(size_t)n * 4 + q] = r;
            }
        }
    } else {
        // Never expected (sz > 22 sigma above mean); slow but correct.
        const int ln = t >> 2;
        const int q = t & 3;
        const float4* x4 = reinterpret_cast<const float4*>(x);
        int n = k * NPB + ln;
        if (n < N) {
            float ax = 0.f, ay = 0.f, az = 0.f, aw = 0.f;
            int deg = 0;
            for (int j = 0; j < sz; ++j) {
                int v = binned[beg + j];
                if ((v >> 22) == ln) {
                    float4 vv = x4[(size_t)(v & 0x3FFFFF) * 4 + q];
                    ax += vv.x; ay += vv.y; az += vv.z; aw += vv.w;
                    ++deg;
                }
            }
            float s = rsqrtf((float)deg + 1.0f);
            float4 r; r.x = ax * s; r.y = ay * s; r.z = az * s; r.w = aw * s;
            reinterpret_cast<float4*>(out)[(size_t)n * 4 + q] = r;
        }
    }
}

extern "C" void kernel_launch(void* const* d_in, const int* in_sizes, int n_in,
                              void* d_out, int out_size, void* d_ws, size_t ws_size,
                              hipStream_t stream) {
    const float* x        = (const float*)d_in[0];
    const int*   edge_dst = (const int*)d_in[1];
    float*       out      = (float*)d_out;

    const int E = in_sizes[1];                    // 3,200,000
    const int N = out_size / DFEAT;               // 100,000
    const int B = (N + NPB - 1) >> NPB_SHIFT;     // 1563 buckets
    const int nblocks = (E + EB - 1) / EB;        // 196 bin blocks
    const int M = B * nblocks;                    // ~306k hist entries

    // ws: binned(int E) | hist(int M) | bucketTotal(B) | bucketBase(B+1) ~ 14 MB
    int* binned      = (int*)d_ws;
    int* hist        = binned + E;
    int* bucketTotal = hist + M;
    int* bucketBase  = bucketTotal + B;

    na_bin_kernel<<<nblocks, BIN_THREADS, B * sizeof(int), stream>>>(
        edge_dst, hist, E, B, nblocks);
    na_row_scan<<<B, 64, 0, stream>>>(hist, bucketTotal, nblocks);
    na_base_scan<<<1, 1024, 0, stream>>>(bucketTotal, bucketBase, B);
    na_scatter_fused<<<nblocks, BIN_THREADS, B * sizeof(int), stream>>>(
        edge_dst, hist, bucketBase, binned, E, B, nblocks);
    na_sort_gather<<<B, 256, 0, stream>>>(x, binned, bucketBase, out, N);
}